// Round 9
// baseline (356.661 us; speedup 1.0000x reference)
//
#include <hip/hip_runtime.h>
#include <math.h>

#define L 256
#define CZ 128
#define NH 4
#define HD 32
#define P (L*L)            // 65536
#define NTOT (CZ*P)        // 8388608
#define EPSV 1e-5f
#define SCALE 0.17677669529663687f   // 1/sqrt(32)
#define LOG2E 1.4426950408889634f
#define SC2   (SCALE*LOG2E)

typedef unsigned short u16;
typedef _Float16 f16;
typedef __attribute__((ext_vector_type(8))) _Float16 f16x8;
typedef __attribute__((ext_vector_type(4))) _Float16 f16x4;
typedef __attribute__((ext_vector_type(4))) float    f32x4;

__device__ __forceinline__ float bu2f(u16 u){ return __uint_as_float(((unsigned)u) << 16); }
__device__ __forceinline__ u16 f2bu(float x){
  unsigned u = __float_as_uint(x);
  return (u16)((u + 0x7fffu + ((u >> 16) & 1u)) >> 16);   // RNE
}

__device__ __forceinline__ float ldr(bool fp32, const void* p, size_t i){
  return fp32 ? ((const float*)p)[i] : bu2f(((const u16*)p)[i]);
}
__device__ __forceinline__ void str(bool fp32, void* p, size_t i, float v){
  if (fp32) ((float*)p)[i] = v; else ((u16*)p)[i] = f2bu(v);
}
template<bool FP32>
__device__ __forceinline__ float ldin(const void* p, size_t i){
  return FP32 ? ((const float*)p)[i] : bu2f(((const u16*)p)[i]);
}
template<bool FP32>
__device__ __forceinline__ void stout(void* p, size_t i, float v){
  if (FP32) ((float*)p)[i] = v; else ((u16*)p)[i] = f2bu(v);
}

__device__ __forceinline__ void glds16(const void* g, void* l){
  __builtin_amdgcn_global_load_lds((const __attribute__((address_space(1))) void*)g,
                                   (__attribute__((address_space(3))) void*)l, 16, 0, 0);
}

// ---- workspace layout (float offsets) ----
#define OFF_WQT   16                  // f16 q/k/v/g weights [proj][oc][cin] (128 KB)
#define OFF_WKT   (OFF_WQT+16384)
#define OFF_WVT   (OFF_WKT+16384)     // f16 wrep2 [oc][hc2=h*32+c] (32 KB)
#define OFF_WGT   (OFF_WVT+16384)     // free
#define OFF_WREPT (OFF_WGT+16384)     // f32 [cin][oc] (fallback out_proj)
#define OFF_WBT   (OFF_WREPT+16384)   // 512 floats [cin][h]
#define OFF_BGF   (OFF_WBT+512)       // 128
#define OFF_BREPF (OFF_BGF+128)       // 128
#define OFF_BIAS  (OFF_BREPF+128)     // NH*P floats [h][j][kk]  (big path: (bias-4)*log2e)
#define OFF_XN    344848              // f16 XN[i][cb=16][j=256][8] = 16.78 MB
#define OFF_ATTO  (OFF_XN+4194304)    // f16 ao3[h][i*256+j][c=32] = 16.78 MB  (h-major)
#define WS_NEED   (((size_t)OFF_ATTO + 4194304ull)*4ull)

#define GUARD(ws) if (((((const volatile int*)(ws))[2]) != 0) != FP32) return;
#define RFLAG(ws) (((const volatile int*)(ws))[2] != 0)

// ---- dtype detect + zero (stats + bias accumulators) ----
__global__ __launch_bounds__(256) void detect_zero(const void* pair, float* ws){
  int b = blockIdx.x, t = threadIdx.x;
  if (b > 0){
    ((float4*)(ws + OFF_BIAS))[(size_t)(b-1)*256 + t] = float4{0.f,0.f,0.f,0.f};
    return;
  }
  const u16* u = (const u16*)pair;
  int big = 0;
  for (int k = t; k < 2048; k += 256){
    float av = fabsf(bu2f(u[k]));
    if (!(av < 1e4f)) big = 1;
  }
  __shared__ int sb[256];
  sb[t] = big; __syncthreads();
  for (int off = 128; off > 0; off >>= 1){
    if (t < off) sb[t] |= sb[t+off];
    __syncthreads();
  }
  if (t == 0){ ((int*)ws)[2] = sb[0]; ws[0] = 0.f; ws[1] = 0.f; }
}

// ---- fused weight-prep (blocks<64) + global mean/sumsq (all 2048 blocks) ----
__global__ __launch_bounds__(256) void lnprep(const void* __restrict__ pair,
    const void* wq, const void* wk, const void* wv, const void* wg,
    const void* wrep, const void* wb, const void* bg, const void* brep, float* ws){
  bool fp32 = RFLAG(ws);
  int b = blockIdx.x, t = threadIdx.x;
  if (b < 64){
    int idx = b*256 + t;
    int oc = idx >> 7, cin = idx & 127;
    f16* wf = (f16*)(ws + OFF_WQT);
    wf[0*16384 + idx] = (f16)ldr(fp32, wq, idx);
    wf[1*16384 + idx] = (f16)ldr(fp32, wk, idx);
    wf[2*16384 + idx] = (f16)ldr(fp32, wv, idx);
    wf[3*16384 + idx] = (f16)ldr(fp32, wg, idx);
    float wr = ldr(fp32, wrep, idx);
    ws[OFF_WREPT + cin*128 + oc] = wr;
    ((f16*)(ws + OFF_WVT))[oc*128 + (cin&3)*32 + (cin>>2)] = (f16)wr;
    if (idx < 512){ int h = idx >> 7, ci = idx & 127; ws[OFF_WBT + ci*4 + h] = ldr(fp32, wb, idx); }
    if (idx < 128){ ws[OFF_BGF + idx] = ldr(fp32, bg, idx); ws[OFF_BREPF + idx] = ldr(fp32, brep, idx); }
  }
  int g = b*256 + t;
  float s = 0.f, ss = 0.f;
  if (fp32){
    #pragma unroll
    for (int u = 0; u < 4; ++u){
      float4 v = ((const float4*)pair)[(size_t)u*524288 + g];
      s += v.x+v.y+v.z+v.w;
      ss += v.x*v.x + v.y*v.y + v.z*v.z + v.w*v.w;
    }
  } else {
    #pragma unroll
    for (int u = 0; u < 4; ++u){
      ushort4 v = ((const ushort4*)pair)[(size_t)u*524288 + g];
      float a = bu2f(v.x), bq = bu2f(v.y), c = bu2f(v.z), d = bu2f(v.w);
      s += a+bq+c+d; ss += a*a+bq*bq+c*c+d*d;
    }
  }
  __shared__ float sa[256], sbf[256];
  sa[t] = s; sbf[t] = ss;
  __syncthreads();
  for (int off = 128; off > 0; off >>= 1){
    if (t < off){ sa[t] += sa[t+off]; sbf[t] += sbf[t+off]; }
    __syncthreads();
  }
  if (t == 0){ atomicAdd(&ws[0], sa[0]); atomicAdd(&ws[1], sbf[0]); }
}

// ==================== BIG PATH ====================

// ---- xnorm: LN -> f16 XN + fused bias partials, table pre-scaled by log2e, -4 folded ----
__global__ __launch_bounds__(256) void xnorm(const void* __restrict__ pair,
    const void* __restrict__ gamma, const void* __restrict__ beta, float* __restrict__ ws){
  bool fp32 = RFLAG(ws);
  int a = blockIdx.x & 255, q = blockIdx.x >> 8;
  int t = threadIdx.x;
  int cq = t >> 6, b64 = t & 63, j4 = b64 << 2;
  float mu   = ws[0] * (1.0f/NTOT);
  float var  = ws[1] * (1.0f/NTOT) - mu*mu;
  float rstd = rsqrtf(var + EPSV);
  f16 hv[4][8];
  float pb[4][4];
  #pragma unroll
  for (int col = 0; col < 4; ++col)
    #pragma unroll
    for (int h = 0; h < 4; ++h) pb[col][h] = 0.f;
  #pragma unroll
  for (int ce = 0; ce < 8; ++ce){
    int c = q*32 + cq*8 + ce;
    size_t vi = (size_t)c*16384 + (size_t)a*64 + b64;
    float p0,p1,p2,p3, g0,g1,g2,g3, e0,e1,e2,e3;
    if (fp32){
      float4 pv = ((const float4*)pair)[vi];
      float4 gv = ((const float4*)gamma)[vi];
      float4 bv = ((const float4*)beta)[vi];
      p0=pv.x;p1=pv.y;p2=pv.z;p3=pv.w; g0=gv.x;g1=gv.y;g2=gv.z;g3=gv.w; e0=bv.x;e1=bv.y;e2=bv.z;e3=bv.w;
    } else {
      ushort4 pv = ((const ushort4*)pair)[vi];
      ushort4 gv = ((const ushort4*)gamma)[vi];
      ushort4 bv = ((const ushort4*)beta)[vi];
      p0=bu2f(pv.x);p1=bu2f(pv.y);p2=bu2f(pv.z);p3=bu2f(pv.w);
      g0=bu2f(gv.x);g1=bu2f(gv.y);g2=bu2f(gv.z);g3=bu2f(gv.w);
      e0=bu2f(bv.x);e1=bu2f(bv.y);e2=bu2f(bv.z);e3=bu2f(bv.w);
    }
    float x0 = (p0-mu)*rstd*g0 + e0;
    float x1 = (p1-mu)*rstd*g1 + e1;
    float x2 = (p2-mu)*rstd*g2 + e2;
    float x3 = (p3-mu)*rstd*g3 + e3;
    hv[0][ce] = (f16)x0; hv[1][ce] = (f16)x1; hv[2][ce] = (f16)x2; hv[3][ce] = (f16)x3;
    float4 w4 = *(const float4*)(ws + OFF_WBT + c*4);
    pb[0][0] = fmaf(w4.x, x0, pb[0][0]); pb[0][1] = fmaf(w4.y, x0, pb[0][1]);
    pb[0][2] = fmaf(w4.z, x0, pb[0][2]); pb[0][3] = fmaf(w4.w, x0, pb[0][3]);
    pb[1][0] = fmaf(w4.x, x1, pb[1][0]); pb[1][1] = fmaf(w4.y, x1, pb[1][1]);
    pb[1][2] = fmaf(w4.z, x1, pb[1][2]); pb[1][3] = fmaf(w4.w, x1, pb[1][3]);
    pb[2][0] = fmaf(w4.x, x2, pb[2][0]); pb[2][1] = fmaf(w4.y, x2, pb[2][1]);
    pb[2][2] = fmaf(w4.z, x2, pb[2][2]); pb[2][3] = fmaf(w4.w, x2, pb[2][3]);
    pb[3][0] = fmaf(w4.x, x3, pb[3][0]); pb[3][1] = fmaf(w4.y, x3, pb[3][1]);
    pb[3][2] = fmaf(w4.z, x3, pb[3][2]); pb[3][3] = fmaf(w4.w, x3, pb[3][3]);
  }
  char* xnb = (char*)ws + (size_t)OFF_XN*4;
  int cb = q*4 + cq;
  #pragma unroll
  for (int col = 0; col < 4; ++col){
    f16x8 v;
    #pragma unroll
    for (int ce = 0; ce < 8; ++ce) v[ce] = hv[col][ce];
    *(f16x8*)(xnb + ((((size_t)a*16 + cb)*256) + (j4+col))*16) = v;
  }
  __shared__ float sbb[4][64][16];
  #pragma unroll
  for (int col = 0; col < 4; ++col)
    #pragma unroll
    for (int h = 0; h < 4; ++h) sbb[cq][b64][h*4+col] = pb[col][h];
  __syncthreads();
  #pragma unroll
  for (int k = 0; k < 4; ++k){
    int lin = k*256 + t;
    int bb = lin >> 4, hc = lin & 15;
    float v = sbb[0][bb][hc] + sbb[1][bb][hc] + sbb[2][bb][hc] + sbb[3][bb][hc];
    int h = hc >> 2, col = hc & 3;
    atomicAdd(&ws[OFF_BIAS + h*P + a*256 + bb*4 + col], fmaf(v, LOG2E, -LOG2E));
  }
}

// ---- attn_xn v6: 5 blocks/CU (LDS exact-fit), exp2 path, unrolled barrier-free phase 4 ----
__global__ __launch_bounds__(256, 5) void attn_xn(float* __restrict__ ws){
  __shared__ __align__(16) char smem[32768];
  char* Ab = smem;
  char* Bb = smem + 16384;
  const int t = threadIdx.x;
  int bid = blockIdx.x;
  int W = (bid & 7)*128 + (bid >> 3);          // per-XCD: 32 i-rows x all 4 h
  const int i = W >> 2, h = W & 3;
  const int w = t >> 6, l = t & 63;
  const int l15 = l & 15, l4 = l >> 4;
  const char* xnb = (const char*)ws + (size_t)OFF_XN*4 + (size_t)i*65536;
  const f16* wf = (const f16*)(ws + OFF_WQT);

  auto stage = [&](int q){
    #pragma unroll
    for (int cbl = 0; cbl < 4; ++cbl){
      int jsrc = (w*64 + l) ^ cbl;
      const char* src = xnb + (size_t)((q*4 + cbl)*4096) + (size_t)jsrc*16;
      glds16(src, Ab + cbl*4096 + w*1024);
    }
  };

  f32x4 acc[2][4][2];
  auto projpass = [&](int pr0){
    #pragma unroll
    for (int pp = 0; pp < 2; ++pp)
      #pragma unroll
      for (int mj = 0; mj < 4; ++mj)
        #pragma unroll
        for (int nt = 0; nt < 2; ++nt) acc[pp][mj][nt] = f32x4{0.f,0.f,0.f,0.f};
    #pragma unroll
    for (int q = 0; q < 4; ++q){
      __syncthreads();
      f16x8 A[4];
      #pragma unroll
      for (int mj = 0; mj < 4; ++mj){
        int j = 64*w + 16*mj + l15;
        A[mj] = *(const f16x8*)(Ab + l4*4096 + ((j ^ l4)*16));
      }
      __syncthreads();
      if (q < 3) stage(q+1);
      #pragma unroll
      for (int pp = 0; pp < 2; ++pp){
        #pragma unroll
        for (int nt = 0; nt < 2; ++nt){
          int o = h*32 + nt*16 + l15;
          f16x8 Bf = *(const f16x8*)(wf + (pr0+pp)*16384 + o*128 + q*32 + 8*l4);
          #pragma unroll
          for (int mj = 0; mj < 4; ++mj)
            acc[pp][mj][nt] = __builtin_amdgcn_mfma_f32_16x16x32_f16(A[mj], Bf, acc[pp][mj][nt], 0, 0, 0);
        }
      }
    }
  };

  // ---- pass 1: Q, K ----
  stage(0);
  projpass(0);
  __syncthreads();
  stage(0);                                    // pass-2 restage (L2-hot)
  #pragma unroll
  for (int mj = 0; mj < 4; ++mj){
    #pragma unroll
    for (int nt = 0; nt < 2; ++nt){
      int ob = 2*nt + (l15 >> 3), oe = l15 & 7;
      int kb4 = 64*w + 16*mj + 4*l4;
      #pragma unroll
      for (int r = 0; r < 4; ++r)
        *(f16*)(Bb + ((ob*4096 + (kb4+r)*16 + oe*2) ^ ((ob&3)<<4))) = (f16)acc[0][mj][nt][r];
    }
  }
  __syncthreads();
  f16x8 qa[4];
  #pragma unroll
  for (int mj = 0; mj < 4; ++mj){
    int j = 64*w + 16*mj + l15;
    qa[mj] = *(const f16x8*)(Bb + ((l4*4096 + j*16) ^ ((l4&3)<<4)));
  }
  __syncthreads();
  #pragma unroll
  for (int mj = 0; mj < 4; ++mj){
    #pragma unroll
    for (int nt = 0; nt < 2; ++nt){
      int ob = 2*nt + (l15 >> 3), oe = l15 & 7;
      int kb4 = 64*w + 16*mj + 4*l4;
      #pragma unroll
      for (int r = 0; r < 4; ++r)
        *(f16*)(Bb + ((ob*4096 + (kb4+r)*16 + oe*2) ^ ((ob&3)<<4))) = (f16)acc[1][mj][nt][r];
    }
  }

  // ---- pass 2: V, G ----
  projpass(2);
  f16x4 gsh[4][2];
  #pragma unroll
  for (int mj = 0; mj < 4; ++mj){
    #pragma unroll
    for (int nt = 0; nt < 2; ++nt){
      float bgv = ws[OFF_BGF + h*32 + nt*16 + l15];
      #pragma unroll
      for (int r = 0; r < 4; ++r){
        float z = acc[1][mj][nt][r] + bgv;
        gsh[mj][nt][r] = (f16)(1.0f/(1.0f + __expf(-z)));
      }
    }
  }
  __syncthreads();
  #pragma unroll
  for (int mj = 0; mj < 4; ++mj){
    #pragma unroll
    for (int nt = 0; nt < 2; ++nt){
      int c = nt*16 + l15;
      int kkq = 16*w + 4*mj + l4;
      f16x4 pv;
      #pragma unroll
      for (int r = 0; r < 4; ++r) pv[r] = (f16)acc[0][mj][nt][r];
      *(f16x4*)(Ab + kkq*256 + ((c*8) ^ (l4<<3))) = pv;
    }
  }
  __syncthreads();

  // ---- phase 4: fully unrolled, barrier-free; exp2 path ----
  f32x4 oacc[4][2];
  #pragma unroll
  for (int mj = 0; mj < 4; ++mj)
    #pragma unroll
    for (int nt = 0; nt < 2; ++nt) oacc[mj][nt] = f32x4{0.f,0.f,0.f,0.f};
  float lp[4] = {0.f,0.f,0.f,0.f};
  const float* bias2 = ws + OFF_BIAS + (size_t)h*P;   // (bias-4)*log2e
  const f32x4 zz = {0.f,0.f,0.f,0.f};

  #pragma unroll
  for (int kt = 0; kt < 8; ++kt){
    int kk0 = kt*32, kkq0 = kt*8;
    float4 bvv[4][2];
    #pragma unroll
    for (int mj = 0; mj < 4; ++mj){
      const float* bp = bias2 + (size_t)(64*w + 16*mj + l15)*256 + kk0 + 4*l4;
      bvv[mj][0] = *(const float4*)bp;
      bvv[mj][1] = *(const float4*)(bp + 16);
    }
    f16x8 kbf[2];
    #pragma unroll
    for (int tt = 0; tt < 2; ++tt)
      kbf[tt] = *(const f16x8*)(Bb + ((l4*4096 + (kk0+16*tt+l15)*16) ^ ((l4&3)<<4)));
    f16x4 vb[2][2];
    #pragma unroll
    for (int tt = 0; tt < 2; ++tt)
      #pragma unroll
      for (int nt = 0; nt < 2; ++nt)
        vb[tt][nt] = *(const f16x4*)(Ab + (kkq0+4*tt+l4)*256 + ((((l15+16*nt)*8)) ^ (l4<<3)));
    #pragma unroll
    for (int mj = 0; mj < 4; ++mj){
      #pragma unroll
      for (int tt = 0; tt < 2; ++tt){
        f32x4 s = __builtin_amdgcn_mfma_f32_16x16x32_f16(kbf[tt], qa[mj], zz, 0, 0, 0);
        float4 bv = bvv[mj][tt];
        f16x4 pa;
        {
          float e0 = exp2f(fmaf(s[0], SC2, bv.x));
          float e1 = exp2f(fmaf(s[1], SC2, bv.y));
          float e2 = exp2f(fmaf(s[2], SC2, bv.z));
          float e3 = exp2f(fmaf(s[3], SC2, bv.w));
          lp[mj] += (e0+e1)+(e2+e3);
          pa[0]=(f16)e0; pa[1]=(f16)e1; pa[2]=(f16)e2; pa[3]=(f16)e3;
        }
        #pragma unroll
        for (int nt = 0; nt < 2; ++nt)
          oacc[mj][nt] = __builtin_amdgcn_mfma_f32_16x16x16f16(pa, vb[tt][nt], oacc[mj][nt], 0, 0, 0);
      }
    }
  }

  // ---- epilogue ----
  float inv[4];
  #pragma unroll
  for (int mj = 0; mj < 4; ++mj){
    float v = lp[mj];
    v += __shfl_xor(v, 16);
    v += __shfl_xor(v, 32);
    inv[mj] = 1.0f / v;
  }
  __syncthreads();
  #pragma unroll
  for (int mj = 0; mj < 4; ++mj){
    #pragma unroll
    for (int r = 0; r < 4; ++r){
      float iv = __shfl(inv[mj], 20*l4 + r);
      int j = 64*w + 16*mj + 4*l4 + r;
      int swz = ((j>>2)&3)<<4;
      #pragma unroll
      for (int nt = 0; nt < 2; ++nt){
        int c = nt*16 + l15;
        float ov = oacc[mj][nt][r] * iv * (float)gsh[mj][nt][r];
        *(f16*)(Bb + ((j*64 + c*2) ^ swz)) = (f16)ov;
      }
    }
  }
  __syncthreads();
  char* ao = (char*)ws + (size_t)OFF_ATTO*4 + (size_t)h*4194304 + ((size_t)i*256)*64;
  #pragma unroll
  for (int u = 0; u < 4; ++u){
    int lin = u*256 + t;
    int j = lin >> 2;
    f16x8 v = *(const f16x8*)(Bb + ((j*64 + (lin&3)*16) ^ (((j>>2)&3)<<4)));
    *(f16x8*)(ao + (size_t)lin*16) = v;        // wave-contiguous 1KB stores
  }
}

// ---- out_proj via MFMA from ao3 + wrep2 (5 blocks/CU) ----
__global__ __launch_bounds__(256, 5) void out_proj_mf(float* __restrict__ ws, void* __restrict__ outp){
  bool fp32 = RFLAG(ws);
  __shared__ __align__(16) char smem[32768];
  char* Ab = smem;
  char* Ob = smem + 16384;
  const int t = threadIdx.x;
  int bid = blockIdx.x;
  int W = (bid & 7)*128 + (bid >> 3);
  const int i = W >> 2, oh = W & 3;
  const int w = t >> 6, l = t & 63;
  const int l15 = l & 15, l4 = l >> 4;
  const char* aob = (const char*)ws + (size_t)OFF_ATTO*4;
  const f16* w2 = (const f16*)(ws + OFF_WVT);

  auto stage = [&](int q){
    #pragma unroll
    for (int cbl = 0; cbl < 4; ++cbl){
      int jsrc = (w*64 + l) ^ cbl;
      const char* src = aob + (size_t)q*4194304 + ((size_t)i*256 + jsrc)*64 + cbl*16;
      glds16(src, Ab + cbl*4096 + w*1024);
    }
  };

  f32x4 acc[2][4];
  #pragma unroll
  for (int nt = 0; nt < 2; ++nt)
    #pragma unroll
    for (int mj = 0; mj < 4; ++mj) acc[nt][mj] = f32x4{0.f,0.f,0.f,0.f};

  stage(0);
  #pragma unroll
  for (int q = 0; q < 4; ++q){
    __syncthreads();
    f16x8 A[4];
    #pragma unroll
    for (int mj = 0; mj < 4; ++mj){
      int j = 64*w + 16*mj + l15;
      A[mj] = *(const f16x8*)(Ab + l4*4096 + ((j ^ l4)*16));
    }
    __syncthreads();
    if (q < 3) stage(q+1);
    #pragma unroll
    for (int nt = 0; nt < 2; ++nt){
      int oc = oh*32 + nt*16 + l15;
      f16x8 Bf = *(const f16x8*)(w2 + oc*128 + q*32 + 8*l4);
      #pragma unroll
      for (int mj = 0; mj < 4; ++mj)
        acc[nt][mj] = __builtin_amdgcn_mfma_f32_16x16x32_f16(A[mj], Bf, acc[nt][mj], 0, 0, 0);
    }
  }
  #pragma unroll
  for (int nt = 0; nt < 2; ++nt){
    __syncthreads();
    #pragma unroll
    for (int mj = 0; mj < 4; ++mj){
      #pragma unroll
      for (int r = 0; r < 4; ++r){
        int j = 64*w + 16*mj + 4*l4 + r;
        *(float*)(Ob + l15*1024 + ((j*4) ^ ((l15&7)<<4))) = acc[nt][mj][r];
      }
    }
    __syncthreads();
    #pragma unroll
    for (int o2 = 0; o2 < 16; ++o2){
      int oc = oh*32 + nt*16 + o2;
      float v = *(const float*)(Ob + o2*1024 + ((t*4) ^ ((o2&7)<<4)));
      str(fp32, outp, (size_t)oc*P + (size_t)i*L + t, v + ws[OFF_BREPF + oc]);
    }
  }
}

// ==================== FALLBACK PATH (dormant when ws is big) ====================

template<bool FP32>
__global__ __launch_bounds__(256) void bias_old(const void* __restrict__ pair,
    const void* __restrict__ gamma, const void* __restrict__ beta, float* __restrict__ ws){
  GUARD(ws);
  int a = blockIdx.x & 255, q = blockIdx.x >> 8, b = threadIdx.x;
  float mu   = ws[0] * (1.0f/NTOT);
  float var  = ws[1] * (1.0f/NTOT) - mu*mu;
  float rstd = rsqrtf(var + EPSV);
  float a0=0.f, a1=0.f, a2=0.f, a3=0.f;
  int c0 = q*32;
  for (int cc = 0; cc < 32; ++cc){
    int c = c0 + cc;
    size_t idx = (size_t)c*P + (size_t)a*L + b;
    float xv = (ldin<FP32>(pair,idx) - mu)*rstd*ldin<FP32>(gamma,idx) + ldin<FP32>(beta,idx);
    const float* w4 = ws + OFF_WBT + c*4;
    a0 = fmaf(w4[0], xv, a0); a1 = fmaf(w4[1], xv, a1);
    a2 = fmaf(w4[2], xv, a2); a3 = fmaf(w4[3], xv, a3);
  }
  atomicAdd(&ws[OFF_BIAS + 0*P + a*L + b], a0);
  atomicAdd(&ws[OFF_BIAS + 1*P + a*L + b], a1);
  atomicAdd(&ws[OFF_BIAS + 2*P + a*L + b], a2);
  atomicAdd(&ws[OFF_BIAS + 3*P + a*L + b], a3);
}

template<bool FP32>
__global__ __launch_bounds__(256, 2) void attn_old(const void* __restrict__ pair,
    const void* __restrict__ gamma, const void* __restrict__ beta,
    float* __restrict__ ws, void* __restrict__ outp){
  GUARD(ws);
  __shared__ __align__(16) char smem[65536];
  char* Ab  = smem;
  char* KTb = smem + 32768;
  char* V2b = smem + 49152;
  const int t = threadIdx.x;
  const int h = blockIdx.x >> 8, i = blockIdx.x & 255;
  const int w = t >> 6, l = t & 63;
  const int l15 = l & 15, l4 = l >> 4;
  const float mu   = ws[0] * (1.0f/NTOT);
  const float var  = ws[1] * (1.0f/NTOT) - mu*mu;
  const float rstd = rsqrtf(var + EPSV);
  const f16* wf = (const f16*)(ws + OFF_WQT);
  f32x4 acc[4][4][2];
  #pragma unroll
  for (int pr=0;pr<4;++pr)
    #pragma unroll
    for(int mj=0;mj<4;++mj)
      #pragma unroll
      for(int nt=0;nt<2;++nt) acc[pr][mj][nt] = f32x4{0.f,0.f,0.f,0.f};
  for (int half = 0; half < 2; ++half){
    #pragma unroll
    for (int cb = 0; cb < 8; ++cb){
      int cc0 = cb*8;
      f16x8 hv;
      #pragma unroll
      for (int e = 0; e < 8; ++e){
        size_t idx = (size_t)(half*64 + cc0 + e)*P + (size_t)i*L + t;
        float xv = (ldin<FP32>(pair,idx) - mu)*rstd*ldin<FP32>(gamma,idx) + ldin<FP32>(beta,idx);
        hv[e] = (f16)xv;
      }
      *(f16x8*)(Ab + t*128 + ((cc0*2) ^ ((t&7)<<4))) = hv;
    }
    __syncthreads();
    #pragma unroll
    for (int ksl = 0; ksl < 2; ++ksl){
      int cin0 = half*64 + ksl*32;
      f16x8 A[4];
      #pragma unroll
      for (int mj = 0; mj < 4; ++mj){
        int j = 64*w + 16*mj + l15;
        A[mj] = *(const f16x8*)(Ab + j*128 + (((ksl*32 + 8*l4)*2) ^ ((j&7)<<4)));
      }
      #pragma unroll
      for (int pr = 0; pr < 4; ++pr){
        #pragma unroll
        for (int nt = 0; nt < 2; ++nt){
          int o = h*32 + nt*16 + l15;
          f16x8 Bf = *(const f16x8*)(wf + pr*16384 + o*128 + cin0 + 8*l4);
          #pragma unroll
          for (int mj = 0; mj < 4; ++mj)
            acc[pr][mj][nt] = __builtin_amdgcn_mfma_f32_16x16x32_f16(A[mj], Bf, acc[pr][mj][nt], 0, 0, 0);
        }
      }
    }
    __syncthreads();
  }
  f32x4 gs[4][2];
  #pragma unroll
  for (int mj = 0; mj < 4; ++mj){
    #pragma unroll
    for (int nt = 0; nt < 2; ++nt){
      float bgv = ws[OFF_BGF + h*32 + nt*16 + l15];
      #pragma unroll
      for (int r = 0; r < 4; ++r){
        float z = acc[3][mj][nt][r] + bgv;
        gs[mj][nt][r] = 1.0f/(1.0f + __expf(-z));
      }
    }
  }
  #pragma unroll
  for (int mj = 0; mj < 4; ++mj){
    #pragma unroll
    for (int nt = 0; nt < 2; ++nt){
      int o = nt*16 + l15;
      int kb4 = 64*w + 16*mj + 4*l4;
      f16x4 pv;
      #pragma unroll
      for (int r = 0; r < 4; ++r){
        int j = kb4 + r;
        *(f16*)(Ab  + j*64 + ((o*2) ^ ((j&3)<<4))) = (f16)acc[0][mj][nt][r];
        *(f16*)(KTb + j*64 + ((o*2) ^ ((j&3)<<4))) = (f16)acc[1][mj][nt][r];
        pv[r] = (f16)acc[2][mj][nt][r];
      }
      *(f16x4*)(V2b + o*512 + ((kb4*2) ^ ((o&7)<<4))) = pv;
    }
  }
  __syncthreads();
  f16x8 qa[4];
  #pragma unroll
  for (int mj = 0; mj < 4; ++mj){
    int j = 64*w + 16*mj + l15;
    qa[mj] = *(const f16x8*)(Ab + j*64 + ((16*l4) ^ ((j&3)<<4)));
  }
  __syncthreads();
  f32x4 oacc[4][2];
  #pragma unroll
  for (int mj=0;mj<4;++mj)
    #pragma unroll
    for(int nt=0;nt<2;++nt) oacc[mj][nt] = f32x4{0.f,0.f,0.f,0.f};
  float lp[16];
  #pragma unroll
  for (int u = 0; u < 16; ++u) lp[u] = 0.f;
  const float* bias2 = ws + OFF_BIAS + (size_t)h*P;
  const f32x4 zz = {0.f,0.f,0.f,0.f};
  for (int kt = 0; kt < 4; ++kt){
    int kk0 = kt*64;
    #pragma unroll
    for (int nk = 0; nk < 4; ++nk){
      int kkr = kk0 + nk*16 + l15;
      f16x8 kbf = *(const f16x8*)(KTb + kkr*64 + ((16*l4) ^ ((kkr&3)<<4)));
      #pragma unroll
      for (int mj = 0; mj < 4; ++mj){
        f32x4 s = __builtin_amdgcn_mfma_f32_16x16x32_f16(qa[mj], kbf, zz, 0, 0, 0);
        #pragma unroll
        for (int r = 0; r < 4; ++r){
          int j = 64*w + 16*mj + 4*l4 + r;
          float bv = bias2[(size_t)j*L + kkr] - 4.0f;
          float e = __expf(fmaf(s[r], SCALE, bv));
          lp[mj*4+r] += e;
          *(f16*)(Ab + j*128 + (((nk*16+l15)*2) ^ ((j&7)<<4))) = (f16)e;
        }
      }
    }
    __syncthreads();
    #pragma unroll
    for (int ks2 = 0; ks2 < 2; ++ks2){
      f16x8 vb[2];
      #pragma unroll
      for (int nt = 0; nt < 2; ++nt){
        int c = nt*16 + l15;
        vb[nt] = *(const f16x8*)(V2b + c*512 + (((kk0 + ks2*32 + 8*l4)*2) ^ ((c&7)<<4)));
      }
      #pragma unroll
      for (int mj = 0; mj < 4; ++mj){
        int j = 64*w + 16*mj + l15;
        f16x8 pa = *(const f16x8*)(Ab + j*128 + (((ks2*32 + 8*l4)*2) ^ ((j&7)<<4)));
        #pragma unroll
        for (int nt = 0; nt < 2; ++nt)
          oacc[mj][nt] = __builtin_amdgcn_mfma_f32_16x16x32_f16(pa, vb[nt], oacc[mj][nt], 0, 0, 0);
      }
    }
  }
  __syncthreads();
  #pragma unroll
  for (int u = 0; u < 16; ++u){
    float v = lp[u];
    v += __shfl_xor(v, 1);
    v += __shfl_xor(v, 2);
    v += __shfl_xor(v, 4);
    v += __shfl_xor(v, 8);
    lp[u] = 1.0f / v;
  }
  #pragma unroll
  for (int mj = 0; mj < 4; ++mj){
    #pragma unroll
    for (int nt = 0; nt < 2; ++nt){
      int c = nt*16 + l15;
      #pragma unroll
      for (int r = 0; r < 4; ++r){
        int j = 64*w + 16*mj + 4*l4 + r;
        float ov = oacc[mj][nt][r] * lp[mj*4+r] * gs[mj][nt][r];
        *(float*)(Ab + c*1024 + ((j*4) ^ ((c&7)<<4))) = ov;
      }
    }
  }
  __syncthreads();
  #pragma unroll
  for (int c = 0; c < 32; ++c){
    float v = *(const float*)(Ab + c*1024 + ((t*4) ^ ((c&7)<<4)));
    stout<FP32>(outp, (size_t)(c*NH + h)*P + (size_t)i*L + t, v);
  }
}

template<bool FP32>
__global__ __launch_bounds__(256) void out_proj_old(float* __restrict__ ws, void* __restrict__ outp){
  GUARD(ws);
  __shared__ float gos[CZ*65];
  int blk = blockIdx.x;
  int i = blk >> 2, jb = (blk & 3) << 6;
  int t = threadIdx.x;
  for (int u = 0; u < 32; ++u){
    int lin = u*256 + t;
    int m = lin >> 6, p = lin & 63;
    gos[m*65 + p] = ldin<FP32>(outp, (size_t)m*P + (size_t)i*L + jb + p);
  }
  __syncthreads();
  int p = t & 63, w4 = t >> 6;
  int woc = w4*32;
  float acc[32];
  #pragma unroll
  for (int o = 0; o < 32; ++o) acc[o] = 0.f;
  for (int cin = 0; cin < CZ; ++cin){
    float xv = gos[cin*65 + p];
    const float* wrow = ws + OFF_WREPT + cin*128 + woc;
    #pragma unroll
    for (int o = 0; o < 32; ++o) acc[o] = fmaf(wrow[o], xv, acc[o]);
  }
  #pragma unroll
  for (int o = 0; o < 32; ++o){
    int oc = woc + o;
    stout<FP32>(outp, (size_t)oc*P + (size_t)i*L + jb + p, acc[o] + ws[OFF_BREPF + oc]);
  }
}

extern "C" void kernel_launch(void* const* d_in, const int* in_sizes, int n_in,
                              void* d_out, int out_size, void* d_ws, size_t ws_size,
                              hipStream_t stream) {
  (void)in_sizes; (void)n_in; (void)out_size;
  const void* pair  = d_in[0];
  const void* gamma = d_in[1];
  const void* beta  = d_in[2];
  const void* wq    = d_in[3];
  const void* wk    = d_in[4];
  const void* wv    = d_in[5];
  const void* wb    = d_in[6];
  const void* wg    = d_in[7];
  const void* bg    = d_in[8];
  const void* wrep  = d_in[9];
  const void* brep  = d_in[10];
  float* ws = (float*)d_ws;
  bool big = ws_size >= WS_NEED;

  detect_zero<<<257,  256, 0, stream>>>(pair, ws);
  lnprep     <<<2048, 256, 0, stream>>>(pair, wq, wk, wv, wg, wrep, wb, bg, brep, ws);

  if (big){
    xnorm      <<<1024, 256, 0, stream>>>(pair, gamma, beta, ws);
    attn_xn    <<<1024, 256, 0, stream>>>(ws);
    out_proj_mf<<<1024, 256, 0, stream>>>(ws, d_out);
  } else {
    bias_old<false>    <<<1024, 256, 0, stream>>>(pair, gamma, beta, ws);
    bias_old<true>     <<<1024, 256, 0, stream>>>(pair, gamma, beta, ws);
    attn_old<false>    <<<1024, 256, 0, stream>>>(pair, gamma, beta, ws, d_out);
    attn_old<true>     <<<1024, 256, 0, stream>>>(pair, gamma, beta, ws, d_out);
    out_proj_old<false><<<1024, 256, 0, stream>>>(ws, d_out);
    out_proj_old<true> <<<1024, 256, 0, stream>>>(ws, d_out);
  }
}

// Round 10
// 298.487 us; speedup vs baseline: 1.1949x; 1.1949x over previous
//
#include <hip/hip_runtime.h>
#include <math.h>

#define L 256
#define CZ 128
#define NH 4
#define HD 32
#define P (L*L)            // 65536
#define NTOT (CZ*P)        // 8388608
#define EPSV 1e-5f
#define SCALE 0.17677669529663687f   // 1/sqrt(32)
#define LOG2E 1.4426950408889634f
#define SC2   (SCALE*LOG2E)

typedef unsigned short u16;
typedef _Float16 f16;
typedef __attribute__((ext_vector_type(8))) _Float16 f16x8;
typedef __attribute__((ext_vector_type(4))) _Float16 f16x4;
typedef __attribute__((ext_vector_type(4))) float    f32x4;

__device__ __forceinline__ float bu2f(u16 u){ return __uint_as_float(((unsigned)u) << 16); }
__device__ __forceinline__ u16 f2bu(float x){
  unsigned u = __float_as_uint(x);
  return (u16)((u + 0x7fffu + ((u >> 16) & 1u)) >> 16);   // RNE
}

__device__ __forceinline__ float ldr(bool fp32, const void* p, size_t i){
  return fp32 ? ((const float*)p)[i] : bu2f(((const u16*)p)[i]);
}
__device__ __forceinline__ void str(bool fp32, void* p, size_t i, float v){
  if (fp32) ((float*)p)[i] = v; else ((u16*)p)[i] = f2bu(v);
}
template<bool FP32>
__device__ __forceinline__ float ldin(const void* p, size_t i){
  return FP32 ? ((const float*)p)[i] : bu2f(((const u16*)p)[i]);
}
template<bool FP32>
__device__ __forceinline__ void stout(void* p, size_t i, float v){
  if (FP32) ((float*)p)[i] = v; else ((u16*)p)[i] = f2bu(v);
}

__device__ __forceinline__ void glds16(const void* g, void* l){
  __builtin_amdgcn_global_load_lds((const __attribute__((address_space(1))) void*)g,
                                   (__attribute__((address_space(3))) void*)l, 16, 0, 0);
}

// ---- workspace layout (float offsets) ----
#define OFF_WQT   16                  // f16 q/k/v/g weights [proj][oc][cin] (128 KB)
#define OFF_WKT   (OFF_WQT+16384)
#define OFF_WVT   (OFF_WKT+16384)     // f16 wrep2 [oc][hc2=h*32+c] (32 KB)
#define OFF_WGT   (OFF_WVT+16384)     // free
#define OFF_WREPT (OFF_WGT+16384)     // f32 [cin][oc] (fallback out_proj)
#define OFF_WBT   (OFF_WREPT+16384)   // 512 floats [cin][h]
#define OFF_BGF   (OFF_WBT+512)       // 128
#define OFF_BREPF (OFF_BGF+128)       // 128
#define OFF_BIAS  (OFF_BREPF+128)     // NH*P floats [h][j][kk]  (big path: (bias-4)*log2e)
#define OFF_XN    344848              // f16 XN[i][cb=16][j=256][8] = 16.78 MB
#define OFF_ATTO  (OFF_XN+4194304)    // f16 ao3[h][i*256+j][c=32] = 16.78 MB  (h-major)
#define WS_NEED   (((size_t)OFF_ATTO + 4194304ull)*4ull)

#define GUARD(ws) if (((((const volatile int*)(ws))[2]) != 0) != FP32) return;
#define RFLAG(ws) (((const volatile int*)(ws))[2] != 0)

// ---- dtype detect + zero (stats + bias accumulators) ----
__global__ __launch_bounds__(256) void detect_zero(const void* pair, float* ws){
  int b = blockIdx.x, t = threadIdx.x;
  if (b > 0){
    ((float4*)(ws + OFF_BIAS))[(size_t)(b-1)*256 + t] = float4{0.f,0.f,0.f,0.f};
    return;
  }
  const u16* u = (const u16*)pair;
  int big = 0;
  for (int k = t; k < 2048; k += 256){
    float av = fabsf(bu2f(u[k]));
    if (!(av < 1e4f)) big = 1;
  }
  __shared__ int sb[256];
  sb[t] = big; __syncthreads();
  for (int off = 128; off > 0; off >>= 1){
    if (t < off) sb[t] |= sb[t+off];
    __syncthreads();
  }
  if (t == 0){ ((int*)ws)[2] = sb[0]; ws[0] = 0.f; ws[1] = 0.f; }
}

// ---- fused weight-prep (blocks<64) + global mean/sumsq (all 2048 blocks) ----
__global__ __launch_bounds__(256) void lnprep(const void* __restrict__ pair,
    const void* wq, const void* wk, const void* wv, const void* wg,
    const void* wrep, const void* wb, const void* bg, const void* brep, float* ws){
  bool fp32 = RFLAG(ws);
  int b = blockIdx.x, t = threadIdx.x;
  if (b < 64){
    int idx = b*256 + t;
    int oc = idx >> 7, cin = idx & 127;
    f16* wf = (f16*)(ws + OFF_WQT);
    wf[0*16384 + idx] = (f16)ldr(fp32, wq, idx);
    wf[1*16384 + idx] = (f16)ldr(fp32, wk, idx);
    wf[2*16384 + idx] = (f16)ldr(fp32, wv, idx);
    wf[3*16384 + idx] = (f16)ldr(fp32, wg, idx);
    float wr = ldr(fp32, wrep, idx);
    ws[OFF_WREPT + cin*128 + oc] = wr;
    ((f16*)(ws + OFF_WVT))[oc*128 + (cin&3)*32 + (cin>>2)] = (f16)wr;
    if (idx < 512){ int h = idx >> 7, ci = idx & 127; ws[OFF_WBT + ci*4 + h] = ldr(fp32, wb, idx); }
    if (idx < 128){ ws[OFF_BGF + idx] = ldr(fp32, bg, idx); ws[OFF_BREPF + idx] = ldr(fp32, brep, idx); }
  }
  int g = b*256 + t;
  float s = 0.f, ss = 0.f;
  if (fp32){
    #pragma unroll
    for (int u = 0; u < 4; ++u){
      float4 v = ((const float4*)pair)[(size_t)u*524288 + g];
      s += v.x+v.y+v.z+v.w;
      ss += v.x*v.x + v.y*v.y + v.z*v.z + v.w*v.w;
    }
  } else {
    #pragma unroll
    for (int u = 0; u < 4; ++u){
      ushort4 v = ((const ushort4*)pair)[(size_t)u*524288 + g];
      float a = bu2f(v.x), bq = bu2f(v.y), c = bu2f(v.z), d = bu2f(v.w);
      s += a+bq+c+d; ss += a*a+bq*bq+c*c+d*d;
    }
  }
  __shared__ float sa[256], sbf[256];
  sa[t] = s; sbf[t] = ss;
  __syncthreads();
  for (int off = 128; off > 0; off >>= 1){
    if (t < off){ sa[t] += sa[t+off]; sbf[t] += sbf[t+off]; }
    __syncthreads();
  }
  if (t == 0){ atomicAdd(&ws[0], sa[0]); atomicAdd(&ws[1], sbf[0]); }
}

// ==================== BIG PATH ====================

// ---- xnorm: LN -> f16 XN + fused bias partials, table pre-scaled by log2e, -4 folded ----
__global__ __launch_bounds__(256) void xnorm(const void* __restrict__ pair,
    const void* __restrict__ gamma, const void* __restrict__ beta, float* __restrict__ ws){
  bool fp32 = RFLAG(ws);
  int a = blockIdx.x & 255, q = blockIdx.x >> 8;
  int t = threadIdx.x;
  int cq = t >> 6, b64 = t & 63, j4 = b64 << 2;
  float mu   = ws[0] * (1.0f/NTOT);
  float var  = ws[1] * (1.0f/NTOT) - mu*mu;
  float rstd = rsqrtf(var + EPSV);
  f16 hv[4][8];
  float pb[4][4];
  #pragma unroll
  for (int col = 0; col < 4; ++col)
    #pragma unroll
    for (int h = 0; h < 4; ++h) pb[col][h] = 0.f;
  #pragma unroll
  for (int ce = 0; ce < 8; ++ce){
    int c = q*32 + cq*8 + ce;
    size_t vi = (size_t)c*16384 + (size_t)a*64 + b64;
    float p0,p1,p2,p3, g0,g1,g2,g3, e0,e1,e2,e3;
    if (fp32){
      float4 pv = ((const float4*)pair)[vi];
      float4 gv = ((const float4*)gamma)[vi];
      float4 bv = ((const float4*)beta)[vi];
      p0=pv.x;p1=pv.y;p2=pv.z;p3=pv.w; g0=gv.x;g1=gv.y;g2=gv.z;g3=gv.w; e0=bv.x;e1=bv.y;e2=bv.z;e3=bv.w;
    } else {
      ushort4 pv = ((const ushort4*)pair)[vi];
      ushort4 gv = ((const ushort4*)gamma)[vi];
      ushort4 bv = ((const ushort4*)beta)[vi];
      p0=bu2f(pv.x);p1=bu2f(pv.y);p2=bu2f(pv.z);p3=bu2f(pv.w);
      g0=bu2f(gv.x);g1=bu2f(gv.y);g2=bu2f(gv.z);g3=bu2f(gv.w);
      e0=bu2f(bv.x);e1=bu2f(bv.y);e2=bu2f(bv.z);e3=bu2f(bv.w);
    }
    float x0 = (p0-mu)*rstd*g0 + e0;
    float x1 = (p1-mu)*rstd*g1 + e1;
    float x2 = (p2-mu)*rstd*g2 + e2;
    float x3 = (p3-mu)*rstd*g3 + e3;
    hv[0][ce] = (f16)x0; hv[1][ce] = (f16)x1; hv[2][ce] = (f16)x2; hv[3][ce] = (f16)x3;
    float4 w4 = *(const float4*)(ws + OFF_WBT + c*4);
    pb[0][0] = fmaf(w4.x, x0, pb[0][0]); pb[0][1] = fmaf(w4.y, x0, pb[0][1]);
    pb[0][2] = fmaf(w4.z, x0, pb[0][2]); pb[0][3] = fmaf(w4.w, x0, pb[0][3]);
    pb[1][0] = fmaf(w4.x, x1, pb[1][0]); pb[1][1] = fmaf(w4.y, x1, pb[1][1]);
    pb[1][2] = fmaf(w4.z, x1, pb[1][2]); pb[1][3] = fmaf(w4.w, x1, pb[1][3]);
    pb[2][0] = fmaf(w4.x, x2, pb[2][0]); pb[2][1] = fmaf(w4.y, x2, pb[2][1]);
    pb[2][2] = fmaf(w4.z, x2, pb[2][2]); pb[2][3] = fmaf(w4.w, x2, pb[2][3]);
    pb[3][0] = fmaf(w4.x, x3, pb[3][0]); pb[3][1] = fmaf(w4.y, x3, pb[3][1]);
    pb[3][2] = fmaf(w4.z, x3, pb[3][2]); pb[3][3] = fmaf(w4.w, x3, pb[3][3]);
  }
  char* xnb = (char*)ws + (size_t)OFF_XN*4;
  int cb = q*4 + cq;
  #pragma unroll
  for (int col = 0; col < 4; ++col){
    f16x8 v;
    #pragma unroll
    for (int ce = 0; ce < 8; ++ce) v[ce] = hv[col][ce];
    *(f16x8*)(xnb + ((((size_t)a*16 + cb)*256) + (j4+col))*16) = v;
  }
  __shared__ float sbb[4][64][16];
  #pragma unroll
  for (int col = 0; col < 4; ++col)
    #pragma unroll
    for (int h = 0; h < 4; ++h) sbb[cq][b64][h*4+col] = pb[col][h];
  __syncthreads();
  #pragma unroll
  for (int k = 0; k < 4; ++k){
    int lin = k*256 + t;
    int bb = lin >> 4, hc = lin & 15;
    float v = sbb[0][bb][hc] + sbb[1][bb][hc] + sbb[2][bb][hc] + sbb[3][bb][hc];
    int h = hc >> 2, col = hc & 3;
    atomicAdd(&ws[OFF_BIAS + h*P + a*256 + bb*4 + col], fmaf(v, LOG2E, -LOG2E));
  }
}

// ---- attn_xn v7: 4 blocks/CU (no spill), exp2 path, unrolled barrier-free phase 4 ----
__global__ __launch_bounds__(256, 4) void attn_xn(float* __restrict__ ws){
  __shared__ __align__(16) char smem[32768];
  char* Ab = smem;
  char* Bb = smem + 16384;
  const int t = threadIdx.x;
  int bid = blockIdx.x;
  int W = (bid & 7)*128 + (bid >> 3);          // per-XCD: 32 i-rows x all 4 h
  const int i = W >> 2, h = W & 3;
  const int w = t >> 6, l = t & 63;
  const int l15 = l & 15, l4 = l >> 4;
  const char* xnb = (const char*)ws + (size_t)OFF_XN*4 + (size_t)i*65536;
  const f16* wf = (const f16*)(ws + OFF_WQT);

  auto stage = [&](int q){
    #pragma unroll
    for (int cbl = 0; cbl < 4; ++cbl){
      int jsrc = (w*64 + l) ^ cbl;
      const char* src = xnb + (size_t)((q*4 + cbl)*4096) + (size_t)jsrc*16;
      glds16(src, Ab + cbl*4096 + w*1024);
    }
  };

  f32x4 acc[2][4][2];
  auto projpass = [&](int pr0){
    #pragma unroll
    for (int pp = 0; pp < 2; ++pp)
      #pragma unroll
      for (int mj = 0; mj < 4; ++mj)
        #pragma unroll
        for (int nt = 0; nt < 2; ++nt) acc[pp][mj][nt] = f32x4{0.f,0.f,0.f,0.f};
    #pragma unroll
    for (int q = 0; q < 4; ++q){
      __syncthreads();
      f16x8 A[4];
      #pragma unroll
      for (int mj = 0; mj < 4; ++mj){
        int j = 64*w + 16*mj + l15;
        A[mj] = *(const f16x8*)(Ab + l4*4096 + ((j ^ l4)*16));
      }
      __syncthreads();
      if (q < 3) stage(q+1);
      #pragma unroll
      for (int pp = 0; pp < 2; ++pp){
        #pragma unroll
        for (int nt = 0; nt < 2; ++nt){
          int o = h*32 + nt*16 + l15;
          f16x8 Bf = *(const f16x8*)(wf + (pr0+pp)*16384 + o*128 + q*32 + 8*l4);
          #pragma unroll
          for (int mj = 0; mj < 4; ++mj)
            acc[pp][mj][nt] = __builtin_amdgcn_mfma_f32_16x16x32_f16(A[mj], Bf, acc[pp][mj][nt], 0, 0, 0);
        }
      }
    }
  };

  // ---- pass 1: Q, K ----
  stage(0);
  projpass(0);
  __syncthreads();
  stage(0);                                    // pass-2 restage (L2-hot)
  #pragma unroll
  for (int mj = 0; mj < 4; ++mj){
    #pragma unroll
    for (int nt = 0; nt < 2; ++nt){
      int ob = 2*nt + (l15 >> 3), oe = l15 & 7;
      int kb4 = 64*w + 16*mj + 4*l4;
      #pragma unroll
      for (int r = 0; r < 4; ++r)
        *(f16*)(Bb + ((ob*4096 + (kb4+r)*16 + oe*2) ^ ((ob&3)<<4))) = (f16)acc[0][mj][nt][r];
    }
  }
  __syncthreads();
  f16x8 qa[4];
  #pragma unroll
  for (int mj = 0; mj < 4; ++mj){
    int j = 64*w + 16*mj + l15;
    qa[mj] = *(const f16x8*)(Bb + ((l4*4096 + j*16) ^ ((l4&3)<<4)));
  }
  __syncthreads();
  #pragma unroll
  for (int mj = 0; mj < 4; ++mj){
    #pragma unroll
    for (int nt = 0; nt < 2; ++nt){
      int ob = 2*nt + (l15 >> 3), oe = l15 & 7;
      int kb4 = 64*w + 16*mj + 4*l4;
      #pragma unroll
      for (int r = 0; r < 4; ++r)
        *(f16*)(Bb + ((ob*4096 + (kb4+r)*16 + oe*2) ^ ((ob&3)<<4))) = (f16)acc[1][mj][nt][r];
    }
  }

  // ---- pass 2: V, G ----
  projpass(2);
  f16x4 gsh[4][2];
  #pragma unroll
  for (int mj = 0; mj < 4; ++mj){
    #pragma unroll
    for (int nt = 0; nt < 2; ++nt){
      float bgv = ws[OFF_BGF + h*32 + nt*16 + l15];
      #pragma unroll
      for (int r = 0; r < 4; ++r){
        float z = acc[1][mj][nt][r] + bgv;
        gsh[mj][nt][r] = (f16)(1.0f/(1.0f + __expf(-z)));
      }
    }
  }
  __syncthreads();
  #pragma unroll
  for (int mj = 0; mj < 4; ++mj){
    #pragma unroll
    for (int nt = 0; nt < 2; ++nt){
      int c = nt*16 + l15;
      int kkq = 16*w + 4*mj + l4;
      f16x4 pv;
      #pragma unroll
      for (int r = 0; r < 4; ++r) pv[r] = (f16)acc[0][mj][nt][r];
      *(f16x4*)(Ab + kkq*256 + ((c*8) ^ (l4<<3))) = pv;
    }
  }
  __syncthreads();

  // ---- phase 4: fully unrolled, barrier-free; exp2 path ----
  f32x4 oacc[4][2];
  #pragma unroll
  for (int mj = 0; mj < 4; ++mj)
    #pragma unroll
    for (int nt = 0; nt < 2; ++nt) oacc[mj][nt] = f32x4{0.f,0.f,0.f,0.f};
  float lp[4] = {0.f,0.f,0.f,0.f};
  const float* bias2 = ws + OFF_BIAS + (size_t)h*P;   // (bias-4)*log2e
  const f32x4 zz = {0.f,0.f,0.f,0.f};

  #pragma unroll
  for (int kt = 0; kt < 8; ++kt){
    int kk0 = kt*32, kkq0 = kt*8;
    float4 bvv[4][2];
    #pragma unroll
    for (int mj = 0; mj < 4; ++mj){
      const float* bp = bias2 + (size_t)(64*w + 16*mj + l15)*256 + kk0 + 4*l4;
      bvv[mj][0] = *(const float4*)bp;
      bvv[mj][1] = *(const float4*)(bp + 16);
    }
    f16x8 kbf[2];
    #pragma unroll
    for (int tt = 0; tt < 2; ++tt)
      kbf[tt] = *(const f16x8*)(Bb + ((l4*4096 + (kk0+16*tt+l15)*16) ^ ((l4&3)<<4)));
    f16x4 vb[2][2];
    #pragma unroll
    for (int tt = 0; tt < 2; ++tt)
      #pragma unroll
      for (int nt = 0; nt < 2; ++nt)
        vb[tt][nt] = *(const f16x4*)(Ab + (kkq0+4*tt+l4)*256 + ((((l15+16*nt)*8)) ^ (l4<<3)));
    #pragma unroll
    for (int mj = 0; mj < 4; ++mj){
      #pragma unroll
      for (int tt = 0; tt < 2; ++tt){
        f32x4 s = __builtin_amdgcn_mfma_f32_16x16x32_f16(kbf[tt], qa[mj], zz, 0, 0, 0);
        float4 bv = bvv[mj][tt];
        f16x4 pa;
        {
          float e0 = exp2f(fmaf(s[0], SC2, bv.x));
          float e1 = exp2f(fmaf(s[1], SC2, bv.y));
          float e2 = exp2f(fmaf(s[2], SC2, bv.z));
          float e3 = exp2f(fmaf(s[3], SC2, bv.w));
          lp[mj] += (e0+e1)+(e2+e3);
          pa[0]=(f16)e0; pa[1]=(f16)e1; pa[2]=(f16)e2; pa[3]=(f16)e3;
        }
        #pragma unroll
        for (int nt = 0; nt < 2; ++nt)
          oacc[mj][nt] = __builtin_amdgcn_mfma_f32_16x16x16f16(pa, vb[tt][nt], oacc[mj][nt], 0, 0, 0);
      }
    }
  }

  // ---- epilogue ----
  float inv[4];
  #pragma unroll
  for (int mj = 0; mj < 4; ++mj){
    float v = lp[mj];
    v += __shfl_xor(v, 16);
    v += __shfl_xor(v, 32);
    inv[mj] = 1.0f / v;
  }
  __syncthreads();
  #pragma unroll
  for (int mj = 0; mj < 4; ++mj){
    #pragma unroll
    for (int r = 0; r < 4; ++r){
      float iv = __shfl(inv[mj], 20*l4 + r);
      int j = 64*w + 16*mj + 4*l4 + r;
      int swz = ((j>>2)&3)<<4;
      #pragma unroll
      for (int nt = 0; nt < 2; ++nt){
        int c = nt*16 + l15;
        float ov = oacc[mj][nt][r] * iv * (float)gsh[mj][nt][r];
        *(f16*)(Bb + ((j*64 + c*2) ^ swz)) = (f16)ov;
      }
    }
  }
  __syncthreads();
  char* ao = (char*)ws + (size_t)OFF_ATTO*4 + (size_t)h*4194304 + ((size_t)i*256)*64;
  #pragma unroll
  for (int u = 0; u < 4; ++u){
    int lin = u*256 + t;
    int j = lin >> 2;
    f16x8 v = *(const f16x8*)(Bb + ((j*64 + (lin&3)*16) ^ (((j>>2)&3)<<4)));
    *(f16x8*)(ao + (size_t)lin*16) = v;        // wave-contiguous 1KB stores
  }
}

// ---- out_proj via MFMA from ao3 + wrep2 (4 blocks/CU) ----
__global__ __launch_bounds__(256, 4) void out_proj_mf(float* __restrict__ ws, void* __restrict__ outp){
  bool fp32 = RFLAG(ws);
  __shared__ __align__(16) char smem[32768];
  char* Ab = smem;
  char* Ob = smem + 16384;
  const int t = threadIdx.x;
  int bid = blockIdx.x;
  int W = (bid & 7)*128 + (bid >> 3);
  const int i = W >> 2, oh = W & 3;
  const int w = t >> 6, l = t & 63;
  const int l15 = l & 15, l4 = l >> 4;
  const char* aob = (const char*)ws + (size_t)OFF_ATTO*4;
  const f16* w2 = (const f16*)(ws + OFF_WVT);

  auto stage = [&](int q){
    #pragma unroll
    for (int cbl = 0; cbl < 4; ++cbl){
      int jsrc = (w*64 + l) ^ cbl;
      const char* src = aob + (size_t)q*4194304 + ((size_t)i*256 + jsrc)*64 + cbl*16;
      glds16(src, Ab + cbl*4096 + w*1024);
    }
  };

  f32x4 acc[2][4];
  #pragma unroll
  for (int nt = 0; nt < 2; ++nt)
    #pragma unroll
    for (int mj = 0; mj < 4; ++mj) acc[nt][mj] = f32x4{0.f,0.f,0.f,0.f};

  stage(0);
  #pragma unroll
  for (int q = 0; q < 4; ++q){
    __syncthreads();
    f16x8 A[4];
    #pragma unroll
    for (int mj = 0; mj < 4; ++mj){
      int j = 64*w + 16*mj + l15;
      A[mj] = *(const f16x8*)(Ab + l4*4096 + ((j ^ l4)*16));
    }
    __syncthreads();
    if (q < 3) stage(q+1);
    #pragma unroll
    for (int nt = 0; nt < 2; ++nt){
      int oc = oh*32 + nt*16 + l15;
      f16x8 Bf = *(const f16x8*)(w2 + oc*128 + q*32 + 8*l4);
      #pragma unroll
      for (int mj = 0; mj < 4; ++mj)
        acc[nt][mj] = __builtin_amdgcn_mfma_f32_16x16x32_f16(A[mj], Bf, acc[nt][mj], 0, 0, 0);
    }
  }
  #pragma unroll
  for (int nt = 0; nt < 2; ++nt){
    __syncthreads();
    #pragma unroll
    for (int mj = 0; mj < 4; ++mj){
      #pragma unroll
      for (int r = 0; r < 4; ++r){
        int j = 64*w + 16*mj + 4*l4 + r;
        *(float*)(Ob + l15*1024 + ((j*4) ^ ((l15&7)<<4))) = acc[nt][mj][r];
      }
    }
    __syncthreads();
    #pragma unroll
    for (int o2 = 0; o2 < 16; ++o2){
      int oc = oh*32 + nt*16 + o2;
      float v = *(const float*)(Ob + o2*1024 + ((t*4) ^ ((o2&7)<<4)));
      str(fp32, outp, (size_t)oc*P + (size_t)i*L + t, v + ws[OFF_BREPF + oc]);
    }
  }
}

// ==================== FALLBACK PATH (dormant when ws is big) ====================

template<bool FP32>
__global__ __launch_bounds__(256) void bias_old(const void* __restrict__ pair,
    const void* __restrict__ gamma, const void* __restrict__ beta, float* __restrict__ ws){
  GUARD(ws);
  int a = blockIdx.x & 255, q = blockIdx.x >> 8, b = threadIdx.x;
  float mu   = ws[0] * (1.0f/NTOT);
  float var  = ws[1] * (1.0f/NTOT) - mu*mu;
  float rstd = rsqrtf(var + EPSV);
  float a0=0.f, a1=0.f, a2=0.f, a3=0.f;
  int c0 = q*32;
  for (int cc = 0; cc < 32; ++cc){
    int c = c0 + cc;
    size_t idx = (size_t)c*P + (size_t)a*L + b;
    float xv = (ldin<FP32>(pair,idx) - mu)*rstd*ldin<FP32>(gamma,idx) + ldin<FP32>(beta,idx);
    const float* w4 = ws + OFF_WBT + c*4;
    a0 = fmaf(w4[0], xv, a0); a1 = fmaf(w4[1], xv, a1);
    a2 = fmaf(w4[2], xv, a2); a3 = fmaf(w4[3], xv, a3);
  }
  atomicAdd(&ws[OFF_BIAS + 0*P + a*L + b], a0);
  atomicAdd(&ws[OFF_BIAS + 1*P + a*L + b], a1);
  atomicAdd(&ws[OFF_BIAS + 2*P + a*L + b], a2);
  atomicAdd(&ws[OFF_BIAS + 3*P + a*L + b], a3);
}

template<bool FP32>
__global__ __launch_bounds__(256, 2) void attn_old(const void* __restrict__ pair,
    const void* __restrict__ gamma, const void* __restrict__ beta,
    float* __restrict__ ws, void* __restrict__ outp){
  GUARD(ws);
  __shared__ __align__(16) char smem[65536];
  char* Ab  = smem;
  char* KTb = smem + 32768;
  char* V2b = smem + 49152;
  const int t = threadIdx.x;
  const int h = blockIdx.x >> 8, i = blockIdx.x & 255;
  const int w = t >> 6, l = t & 63;
  const int l15 = l & 15, l4 = l >> 4;
  const float mu   = ws[0] * (1.0f/NTOT);
  const float var  = ws[1] * (1.0f/NTOT) - mu*mu;
  const float rstd = rsqrtf(var + EPSV);
  const f16* wf = (const f16*)(ws + OFF_WQT);
  f32x4 acc[4][4][2];
  #pragma unroll
  for (int pr=0;pr<4;++pr)
    #pragma unroll
    for(int mj=0;mj<4;++mj)
      #pragma unroll
      for(int nt=0;nt<2;++nt) acc[pr][mj][nt] = f32x4{0.f,0.f,0.f,0.f};
  for (int half = 0; half < 2; ++half){
    #pragma unroll
    for (int cb = 0; cb < 8; ++cb){
      int cc0 = cb*8;
      f16x8 hv;
      #pragma unroll
      for (int e = 0; e < 8; ++e){
        size_t idx = (size_t)(half*64 + cc0 + e)*P + (size_t)i*L + t;
        float xv = (ldin<FP32>(pair,idx) - mu)*rstd*ldin<FP32>(gamma,idx) + ldin<FP32>(beta,idx);
        hv[e] = (f16)xv;
      }
      *(f16x8*)(Ab + t*128 + ((cc0*2) ^ ((t&7)<<4))) = hv;
    }
    __syncthreads();
    #pragma unroll
    for (int ksl = 0; ksl < 2; ++ksl){
      int cin0 = half*64 + ksl*32;
      f16x8 A[4];
      #pragma unroll
      for (int mj = 0; mj < 4; ++mj){
        int j = 64*w + 16*mj + l15;
        A[mj] = *(const f16x8*)(Ab + j*128 + (((ksl*32 + 8*l4)*2) ^ ((j&7)<<4)));
      }
      #pragma unroll
      for (int pr = 0; pr < 4; ++pr){
        #pragma unroll
        for (int nt = 0; nt < 2; ++nt){
          int o = h*32 + nt*16 + l15;
          f16x8 Bf = *(const f16x8*)(wf + pr*16384 + o*128 + cin0 + 8*l4);
          #pragma unroll
          for (int mj = 0; mj < 4; ++mj)
            acc[pr][mj][nt] = __builtin_amdgcn_mfma_f32_16x16x32_f16(A[mj], Bf, acc[pr][mj][nt], 0, 0, 0);
        }
      }
    }
    __syncthreads();
  }
  f32x4 gs[4][2];
  #pragma unroll
  for (int mj = 0; mj < 4; ++mj){
    #pragma unroll
    for (int nt = 0; nt < 2; ++nt){
      float bgv = ws[OFF_BGF + h*32 + nt*16 + l15];
      #pragma unroll
      for (int r = 0; r < 4; ++r){
        float z = acc[3][mj][nt][r] + bgv;
        gs[mj][nt][r] = 1.0f/(1.0f + __expf(-z));
      }
    }
  }
  #pragma unroll
  for (int mj = 0; mj < 4; ++mj){
    #pragma unroll
    for (int nt = 0; nt < 2; ++nt){
      int o = nt*16 + l15;
      int kb4 = 64*w + 16*mj + 4*l4;
      f16x4 pv;
      #pragma unroll
      for (int r = 0; r < 4; ++r){
        int j = kb4 + r;
        *(f16*)(Ab  + j*64 + ((o*2) ^ ((j&3)<<4))) = (f16)acc[0][mj][nt][r];
        *(f16*)(KTb + j*64 + ((o*2) ^ ((j&3)<<4))) = (f16)acc[1][mj][nt][r];
        pv[r] = (f16)acc[2][mj][nt][r];
      }
      *(f16x4*)(V2b + o*512 + ((kb4*2) ^ ((o&7)<<4))) = pv;
    }
  }
  __syncthreads();
  f16x8 qa[4];
  #pragma unroll
  for (int mj = 0; mj < 4; ++mj){
    int j = 64*w + 16*mj + l15;
    qa[mj] = *(const f16x8*)(Ab + j*64 + ((16*l4) ^ ((j&3)<<4)));
  }
  __syncthreads();
  f32x4 oacc[4][2];
  #pragma unroll
  for (int mj=0;mj<4;++mj)
    #pragma unroll
    for(int nt=0;nt<2;++nt) oacc[mj][nt] = f32x4{0.f,0.f,0.f,0.f};
  float lp[16];
  #pragma unroll
  for (int u = 0; u < 16; ++u) lp[u] = 0.f;
  const float* bias2 = ws + OFF_BIAS + (size_t)h*P;
  const f32x4 zz = {0.f,0.f,0.f,0.f};
  for (int kt = 0; kt < 4; ++kt){
    int kk0 = kt*64;
    #pragma unroll
    for (int nk = 0; nk < 4; ++nk){
      int kkr = kk0 + nk*16 + l15;
      f16x8 kbf = *(const f16x8*)(KTb + kkr*64 + ((16*l4) ^ ((kkr&3)<<4)));
      #pragma unroll
      for (int mj = 0; mj < 4; ++mj){
        f32x4 s = __builtin_amdgcn_mfma_f32_16x16x32_f16(qa[mj], kbf, zz, 0, 0, 0);
        #pragma unroll
        for (int r = 0; r < 4; ++r){
          int j = 64*w + 16*mj + 4*l4 + r;
          float bv = bias2[(size_t)j*L + kkr] - 4.0f;
          float e = __expf(fmaf(s[r], SCALE, bv));
          lp[mj*4+r] += e;
          *(f16*)(Ab + j*128 + (((nk*16+l15)*2) ^ ((j&7)<<4))) = (f16)e;
        }
      }
    }
    __syncthreads();
    #pragma unroll
    for (int ks2 = 0; ks2 < 2; ++ks2){
      f16x8 vb[2];
      #pragma unroll
      for (int nt = 0; nt < 2; ++nt){
        int c = nt*16 + l15;
        vb[nt] = *(const f16x8*)(V2b + c*512 + (((kk0 + ks2*32 + 8*l4)*2) ^ ((c&7)<<4)));
      }
      #pragma unroll
      for (int mj = 0; mj < 4; ++mj){
        int j = 64*w + 16*mj + l15;
        f16x8 pa = *(const f16x8*)(Ab + j*128 + (((ks2*32 + 8*l4)*2) ^ ((j&7)<<4)));
        #pragma unroll
        for (int nt = 0; nt < 2; ++nt)
          oacc[mj][nt] = __builtin_amdgcn_mfma_f32_16x16x32_f16(pa, vb[nt], oacc[mj][nt], 0, 0, 0);
      }
    }
  }
  __syncthreads();
  #pragma unroll
  for (int u = 0; u < 16; ++u){
    float v = lp[u];
    v += __shfl_xor(v, 1);
    v += __shfl_xor(v, 2);
    v += __shfl_xor(v, 4);
    v += __shfl_xor(v, 8);
    lp[u] = 1.0f / v;
  }
  #pragma unroll
  for (int mj = 0; mj < 4; ++mj){
    #pragma unroll
    for (int nt = 0; nt < 2; ++nt){
      int c = nt*16 + l15;
      #pragma unroll
      for (int r = 0; r < 4; ++r){
        int j = 64*w + 16*mj + 4*l4 + r;
        float ov = oacc[mj][nt][r] * lp[mj*4+r] * gs[mj][nt][r];
        *(float*)(Ab + c*1024 + ((j*4) ^ ((c&7)<<4))) = ov;
      }
    }
  }
  __syncthreads();
  #pragma unroll
  for (int c = 0; c < 32; ++c){
    float v = *(const float*)(Ab + c*1024 + ((t*4) ^ ((c&7)<<4)));
    stout<FP32>(outp, (size_t)(c*NH + h)*P + (size_t)i*L + t, v);
  }
}

template<bool FP32>
__global__ __launch_bounds__(256) void out_proj_old(float* __restrict__ ws, void* __restrict__ outp){
  GUARD(ws);
  __shared__ float gos[CZ*65];
  int blk = blockIdx.x;
  int i = blk >> 2, jb = (blk & 3) << 6;
  int t = threadIdx.x;
  for (int u = 0; u < 32; ++u){
    int lin = u*256 + t;
    int m = lin >> 6, p = lin & 63;
    gos[m*65 + p] = ldin<FP32>(outp, (size_t)m*P + (size_t)i*L + jb + p);
  }
  __syncthreads();
  int p = t & 63, w4 = t >> 6;
  int woc = w4*32;
  float acc[32];
  #pragma unroll
  for (int o = 0; o < 32; ++o) acc[o] = 0.f;
  for (int cin = 0; cin < CZ; ++cin){
    float xv = gos[cin*65 + p];
    const float* wrow = ws + OFF_WREPT + cin*128 + woc;
    #pragma unroll
    for (int o = 0; o < 32; ++o) acc[o] = fmaf(wrow[o], xv, acc[o]);
  }
  #pragma unroll
  for (int o = 0; o < 32; ++o){
    int oc = woc + o;
    stout<FP32>(outp, (size_t)oc*P + (size_t)i*L + jb + p, acc[o] + ws[OFF_BREPF + oc]);
  }
}

extern "C" void kernel_launch(void* const* d_in, const int* in_sizes, int n_in,
                              void* d_out, int out_size, void* d_ws, size_t ws_size,
                              hipStream_t stream) {
  (void)in_sizes; (void)n_in; (void)out_size;
  const void* pair  = d_in[0];
  const void* gamma = d_in[1];
  const void* beta  = d_in[2];
  const void* wq    = d_in[3];
  const void* wk    = d_in[4];
  const void* wv    = d_in[5];
  const void* wb    = d_in[6];
  const void* wg    = d_in[7];
  const void* bg    = d_in[8];
  const void* wrep  = d_in[9];
  const void* brep  = d_in[10];
  float* ws = (float*)d_ws;
  bool big = ws_size >= WS_NEED;

  detect_zero<<<257,  256, 0, stream>>>(pair, ws);
  lnprep     <<<2048, 256, 0, stream>>>(pair, wq, wk, wv, wg, wrep, wb, bg, brep, ws);

  if (big){
    xnorm      <<<1024, 256, 0, stream>>>(pair, gamma, beta, ws);
    attn_xn    <<<1024, 256, 0, stream>>>(ws);
    out_proj_mf<<<1024, 256, 0, stream>>>(ws, d_out);
  } else {
    bias_old<false>    <<<1024, 256, 0, stream>>>(pair, gamma, beta, ws);
    bias_old<true>     <<<1024, 256, 0, stream>>>(pair, gamma, beta, ws);
    attn_old<false>    <<<1024, 256, 0, stream>>>(pair, gamma, beta, ws, d_out);
    attn_old<true>     <<<1024, 256, 0, stream>>>(pair, gamma, beta, ws, d_out);
    out_proj_old<false><<<1024, 256, 0, stream>>>(ws, d_out);
    out_proj_old<true> <<<1024, 256, 0, stream>>>(ws, d_out);
  }
}